// Round 1
// baseline (31803.860 us; speedup 1.0000x reference)
//
#include <hip/hip_runtime.h>
#include <math.h>

#define NODE 5
#define TT 512
#define F1 128
#define F3 64
#define NBATCH 8192
#define NB 8          // batch elems per block in RNN kernel
#define TB 32         // time steps staged per x-chunk
#define XS_DIM 325    // 5 + 5*64
#define H2 256
#define EPS 1e-5f

// ---------------------------------------------------------------------------
// Kernel A: the sequential RNN over T=512 steps.
// Block = 256 threads = 8 elems x 32 f-groups. Thread (e,fg) owns a
// [5 nodes x 4 cols] register tile per layer. State+h live in LDS,
// weights stream from global (L1/L2 resident, wave-broadcast addresses).
// ---------------------------------------------------------------------------
__global__ __launch_bounds__(256, 4) void rnn_kernel(
    const float* __restrict__ x, const float* __restrict__ adj,
    const float* __restrict__ W0, const float* __restrict__ b0,
    const float* __restrict__ W1, const float* __restrict__ b1,
    const float* __restrict__ W2, const float* __restrict__ b2,
    float* __restrict__ xs)
{
    __shared__ float s_state[NB][NODE][F3];   // 10240 B
    __shared__ float s_h[NB][NODE][F1];       // 20480 B
    __shared__ float s_x[NB][NODE][TB];       //  5120 B
    __shared__ float s_A[NODE][NODE];
    __shared__ float s_b0[F1], s_b1[F1], s_b2[F3];

    const int tid = threadIdx.x;
    const int e  = tid >> 5;      // 0..7
    const int fg = tid & 31;      // 0..31
    const int bbase = blockIdx.x * NB;

    if (tid < NODE*NODE) {
        int i = tid / NODE, j = tid % NODE;
        s_A[i][j] = adj[j*NODE + i];          // A = adj.T
    }
    if (tid < F1) { s_b0[tid] = b0[tid]; s_b1[tid] = b1[tid]; }
    if (tid < F3) s_b2[tid] = b2[tid];
    for (int i = tid; i < NB*NODE*F3; i += 256) (&s_state[0][0][0])[i] = 0.0f;

    const float4* __restrict__ W0v = (const float4*)W0;   // [65][32]
    const float4* __restrict__ W1v = (const float4*)W1;   // [128][32]
    const float2* __restrict__ W2v = (const float2*)W2;   // [128][32]

    #pragma unroll 1
    for (int tc = 0; tc < TT/TB; ++tc) {
        // stage x chunk: s_x[e][n][t] for TB steps (coalesced 128B rows)
        for (int i = tid; i < NB*NODE*TB; i += 256) {
            int t = i & (TB-1);
            int rest = i >> 5;            // TB==32
            int n = rest % NODE, ee = rest / NODE;
            s_x[ee][n][t] = x[((size_t)(bbase+ee)*NODE + n)*TT + tc*TB + t];
        }
        __syncthreads();

        #pragma unroll 1
        for (int tt = 0; tt < TB; ++tt) {
            // ---------------- layer 1: [x_t | state] (65) -> 128, relu ----
            float sup[NODE][4];
            {
                float4 w = W0v[fg];       // W0 row 0 (multiplies x)
                #pragma unroll
                for (int j = 0; j < NODE; ++j) {
                    float xv = s_x[e][j][tt];
                    sup[j][0] = xv*w.x; sup[j][1] = xv*w.y;
                    sup[j][2] = xv*w.z; sup[j][3] = xv*w.w;
                }
            }
            for (int k = 0; k < F3; k += 4) {
                float st[NODE][4];
                #pragma unroll
                for (int j = 0; j < NODE; ++j) {
                    float4 t4 = *(const float4*)&s_state[e][j][k];
                    st[j][0]=t4.x; st[j][1]=t4.y; st[j][2]=t4.z; st[j][3]=t4.w;
                }
                #pragma unroll
                for (int kk = 0; kk < 4; ++kk) {
                    float4 w = W0v[(k+kk+1)*32 + fg];
                    #pragma unroll
                    for (int j = 0; j < NODE; ++j) {
                        sup[j][0] += st[j][kk]*w.x;
                        sup[j][1] += st[j][kk]*w.y;
                        sup[j][2] += st[j][kk]*w.z;
                        sup[j][3] += st[j][kk]*w.w;
                    }
                }
            }
            #pragma unroll
            for (int i = 0; i < NODE; ++i) {
                float z0 = s_b0[fg*4+0], z1 = s_b0[fg*4+1];
                float z2 = s_b0[fg*4+2], z3 = s_b0[fg*4+3];
                #pragma unroll
                for (int j = 0; j < NODE; ++j) {
                    float a = s_A[i][j];
                    z0 += a*sup[j][0]; z1 += a*sup[j][1];
                    z2 += a*sup[j][2]; z3 += a*sup[j][3];
                }
                float4 r;
                r.x = fmaxf(z0,0.f); r.y = fmaxf(z1,0.f);
                r.z = fmaxf(z2,0.f); r.w = fmaxf(z3,0.f);
                *(float4*)&s_h[e][i][fg*4] = r;
            }
            __syncthreads();

            // ---------------- layer 2: 128 -> 128, relu ------------------
            float sup2[NODE][4];
            #pragma unroll
            for (int j = 0; j < NODE; ++j)
                sup2[j][0]=sup2[j][1]=sup2[j][2]=sup2[j][3]=0.f;
            for (int k = 0; k < F1; k += 4) {
                float hj[NODE][4];
                #pragma unroll
                for (int j = 0; j < NODE; ++j) {
                    float4 t4 = *(const float4*)&s_h[e][j][k];
                    hj[j][0]=t4.x; hj[j][1]=t4.y; hj[j][2]=t4.z; hj[j][3]=t4.w;
                }
                #pragma unroll
                for (int kk = 0; kk < 4; ++kk) {
                    float4 w = W1v[(k+kk)*32 + fg];
                    #pragma unroll
                    for (int j = 0; j < NODE; ++j) {
                        sup2[j][0] += hj[j][kk]*w.x;
                        sup2[j][1] += hj[j][kk]*w.y;
                        sup2[j][2] += hj[j][kk]*w.z;
                        sup2[j][3] += hj[j][kk]*w.w;
                    }
                }
            }
            __syncthreads();   // everyone done READING s_h before overwrite
            #pragma unroll
            for (int i = 0; i < NODE; ++i) {
                float z0 = s_b1[fg*4+0], z1 = s_b1[fg*4+1];
                float z2 = s_b1[fg*4+2], z3 = s_b1[fg*4+3];
                #pragma unroll
                for (int j = 0; j < NODE; ++j) {
                    float a = s_A[i][j];
                    z0 += a*sup2[j][0]; z1 += a*sup2[j][1];
                    z2 += a*sup2[j][2]; z3 += a*sup2[j][3];
                }
                float4 r;
                r.x = fmaxf(z0,0.f); r.y = fmaxf(z1,0.f);
                r.z = fmaxf(z2,0.f); r.w = fmaxf(z3,0.f);
                *(float4*)&s_h[e][i][fg*4] = r;
            }
            __syncthreads();

            // ---------------- layer 3: 128 -> 64, tanh -> state ----------
            float sup3[NODE][2];
            #pragma unroll
            for (int j = 0; j < NODE; ++j) sup3[j][0]=sup3[j][1]=0.f;
            for (int k = 0; k < F1; k += 4) {
                float hj[NODE][4];
                #pragma unroll
                for (int j = 0; j < NODE; ++j) {
                    float4 t4 = *(const float4*)&s_h[e][j][k];
                    hj[j][0]=t4.x; hj[j][1]=t4.y; hj[j][2]=t4.z; hj[j][3]=t4.w;
                }
                #pragma unroll
                for (int kk = 0; kk < 4; ++kk) {
                    float2 w = W2v[(k+kk)*32 + fg];
                    #pragma unroll
                    for (int j = 0; j < NODE; ++j) {
                        sup3[j][0] += hj[j][kk]*w.x;
                        sup3[j][1] += hj[j][kk]*w.y;
                    }
                }
            }
            #pragma unroll
            for (int i = 0; i < NODE; ++i) {
                float z0 = s_b2[fg*2], z1 = s_b2[fg*2+1];
                #pragma unroll
                for (int j = 0; j < NODE; ++j) {
                    float a = s_A[i][j];
                    z0 += a*sup3[j][0]; z1 += a*sup3[j][1];
                }
                s_state[e][i][fg*2  ] = tanhf(z0);
                s_state[e][i][fg*2+1] = tanhf(z1);
            }
            __syncthreads();   // state visible + s_h readers done
        }
    }

    // epilogue: xs[b] = [x_end(5) | state(5*64)]
    #pragma unroll
    for (int n = 0; n < NODE; ++n) {
        xs[(size_t)(bbase+e)*XS_DIM + 5 + n*F3 + fg*2    ] = s_state[e][n][fg*2];
        xs[(size_t)(bbase+e)*XS_DIM + 5 + n*F3 + fg*2 + 1] = s_state[e][n][fg*2+1];
    }
    if (fg < NODE)
        xs[(size_t)(bbase+e)*XS_DIM + fg] = s_x[e][fg][TB-1];
}

// ---------------------------------------------------------------------------
// Kernel B: h = relu(xs @ fc1_w + fc1_b), plus per-column sum / sumsq
// (atomics into zeroed accumulators) for train-mode BatchNorm.
// ---------------------------------------------------------------------------
__global__ __launch_bounds__(256) void fc1_kernel(
    const float* __restrict__ xs, const float* __restrict__ fc1_w,
    const float* __restrict__ fc1_b, float* __restrict__ h,
    float* __restrict__ sums)
{
    __shared__ float s_xs[16*XS_DIM];
    const int tid = threadIdx.x;
    const int r0 = blockIdx.x * 16;
    for (int i = tid; i < 16*XS_DIM; i += 256)
        s_xs[i] = xs[(size_t)r0*XS_DIM + i];
    __syncthreads();

    float acc[16];
    #pragma unroll
    for (int r = 0; r < 16; ++r) acc[r] = 0.f;
    for (int k = 0; k < XS_DIM; ++k) {
        float w = fc1_w[(size_t)k*H2 + tid];
        #pragma unroll
        for (int r = 0; r < 16; ++r) acc[r] += s_xs[r*XS_DIM + k]*w;
    }
    float bb = fc1_b[tid];
    float ls = 0.f, lq = 0.f;
    #pragma unroll
    for (int r = 0; r < 16; ++r) {
        float v = fmaxf(acc[r] + bb, 0.f);
        h[(size_t)(r0+r)*H2 + tid] = v;
        ls += v; lq += v*v;
    }
    atomicAdd(&sums[tid], ls);
    atomicAdd(&sums[H2 + tid], lq);
}

// ---------------------------------------------------------------------------
// Kernel C: BN normalize + fc2 + softmax. One wave per row (4 rows/block).
// ---------------------------------------------------------------------------
__global__ __launch_bounds__(256) void head_kernel(
    const float* __restrict__ h, const float* __restrict__ sums,
    const float* __restrict__ gamma, const float* __restrict__ beta,
    const float* __restrict__ fc2_w, const float* __restrict__ fc2_b,
    float* __restrict__ out)
{
    const int lane = threadIdx.x & 63;
    const int r = blockIdx.x*4 + (threadIdx.x >> 6);
    const int c0 = lane*4;

    float4 hv = *(const float4*)&h[(size_t)r*H2 + c0];
    float hvv[4] = {hv.x, hv.y, hv.z, hv.w};
    float y[4];
    #pragma unroll
    for (int c = 0; c < 4; ++c) {
        int cc = c0 + c;
        float mean = sums[cc] * (1.f/NBATCH);
        float var  = sums[H2+cc]*(1.f/NBATCH) - mean*mean;
        float rstd = rsqrtf(var + EPS);
        y[c] = (hvv[c] - mean)*rstd*gamma[cc] + beta[cc];
    }
    float lg[7];
    #pragma unroll
    for (int j = 0; j < 7; ++j) {
        float p = 0.f;
        #pragma unroll
        for (int c = 0; c < 4; ++c) p += y[c]*fc2_w[(size_t)(c0+c)*7 + j];
        #pragma unroll
        for (int off = 32; off >= 1; off >>= 1) p += __shfl_xor(p, off, 64);
        lg[j] = p + fc2_b[j];
    }
    if (lane == 0) {
        float m = lg[0];
        #pragma unroll
        for (int j = 1; j < 7; ++j) m = fmaxf(m, lg[j]);
        float ev[7]; float s = 0.f;
        #pragma unroll
        for (int j = 0; j < 7; ++j) { ev[j] = expf(lg[j]-m); s += ev[j]; }
        float inv = 1.f/s;
        #pragma unroll
        for (int j = 0; j < 7; ++j) out[(size_t)r*7 + j] = ev[j]*inv;
    }
}

// ---------------------------------------------------------------------------
extern "C" void kernel_launch(void* const* d_in, const int* in_sizes, int n_in,
                              void* d_out, int out_size, void* d_ws, size_t ws_size,
                              hipStream_t stream)
{
    (void)in_sizes; (void)n_in; (void)out_size; (void)ws_size;
    const float* x     = (const float*)d_in[0];
    const float* adj   = (const float*)d_in[1];
    const float* W0    = (const float*)d_in[2];
    const float* b0    = (const float*)d_in[3];
    const float* W1    = (const float*)d_in[4];
    const float* b1    = (const float*)d_in[5];
    const float* W2    = (const float*)d_in[6];
    const float* b2    = (const float*)d_in[7];
    const float* fc1w  = (const float*)d_in[8];
    const float* fc1b  = (const float*)d_in[9];
    const float* gamma = (const float*)d_in[10];
    const float* beta  = (const float*)d_in[11];
    const float* fc2w  = (const float*)d_in[12];
    const float* fc2b  = (const float*)d_in[13];
    float* out = (float*)d_out;

    char* ws = (char*)d_ws;
    float* xs   = (float*)(ws);                                  // 8192*325 f32
    float* hbuf = (float*)(ws + 10649600);                       // 8192*256 f32
    float* sums = (float*)(ws + 10649600 + 8388608);             // 512 f32

    hipMemsetAsync(sums, 0, 512*sizeof(float), stream);
    rnn_kernel<<<NBATCH/NB, 256, 0, stream>>>(x, adj, W0, b0, W1, b1, W2, b2, xs);
    fc1_kernel<<<NBATCH/16, 256, 0, stream>>>(xs, fc1w, fc1b, hbuf, sums);
    head_kernel<<<NBATCH/4, 256, 0, stream>>>(hbuf, sums, gamma, beta, fc2w, fc2b, out);
}

// Round 2
// 3294.598 us; speedup vs baseline: 9.6533x; 9.6533x over previous
//
#include <hip/hip_runtime.h>
#include <math.h>

#define NODE 5
#define TT 512
#define NBATCH 8192
#define NB 16            // batch elems per block
#define MR (NB*NODE)     // 80 rows
#define LDK 144          // padded row stride (halfs) for sg/sh -> 288B rows
#define TB 32
#define XS_DIM 325
#define H2 256
#define EPS 1e-5f

typedef _Float16 h16;
typedef __attribute__((ext_vector_type(8))) _Float16 half8;
typedef __attribute__((ext_vector_type(2))) _Float16 half2v;
typedef __attribute__((ext_vector_type(4))) float float4v;

// ---------------------------------------------------------------------------
// RNN kernel: per step, 3 GCN layers as MFMA GEMMs (M=80, f16 in / f32 acc).
// Uses A(hW) = (Ah)W: node-mix (5x5) runs as cheap VALU passes between GEMMs.
// Weights live in per-wave register B-fragments (loaded once). Activations
// ping-pong between LDS buffers sg (A-operand, mixed) and sh (raw output).
// ---------------------------------------------------------------------------
__global__ __launch_bounds__(256, 2) void rnn_kernel(
    const float* __restrict__ x, const float* __restrict__ adj,
    const float* __restrict__ W0, const float* __restrict__ b0,
    const float* __restrict__ W1, const float* __restrict__ b1,
    const float* __restrict__ W2, const float* __restrict__ b2,
    float* __restrict__ xs)
{
    __shared__ __align__(16) h16 sg[MR*LDK];          // 23040 B  (mixed / A-operand)
    __shared__ __align__(16) h16 sh[MR*LDK];          // 23040 B  (raw layer output)
    __shared__ h16 sx[2][NB][NODE][33];               // 10560 B  (x chunks, dbuf)
    __shared__ float sxg[MR];                         //   320 B  (mixed x for L1)

    const int tid  = threadIdx.x;
    const int lane = tid & 63;
    const int w    = tid >> 6;       // wave 0..3
    const int ln   = lane & 15;
    const int q    = lane >> 4;      // quad 0..3
    const int k0q  = q*8;
    const int bbase = blockIdx.x * NB;

    // ---- A = adj.T in registers (f32 + f16 copies) ----
    float af[NODE][NODE];
    h16   ah[NODE][NODE];
    #pragma unroll
    for (int i = 0; i < NODE; ++i)
        #pragma unroll
        for (int j = 0; j < NODE; ++j) {
            float v = adj[j*NODE + i];
            af[i][j] = v; ah[i][j] = (h16)v;
        }

    // ---- weight B-fragments (held in VGPRs for the whole kernel) ----
    // B-frag layout (16x16x32): lane holds B[k = q*8+j][n = ln] for its n-tile.
    const int nt0 = 2*w, nt1 = 2*w+1, nt3 = w;
    half8 wf0[2][2], wf1f[2][4], wf3[4];
    {
        #pragma unroll
        for (int i = 0; i < 2; ++i) {
            int n = (2*w+i)*16 + ln;
            #pragma unroll
            for (int ks = 0; ks < 2; ++ks) {
                half8 f;
                #pragma unroll
                for (int j = 0; j < 8; ++j)
                    f[j] = (h16)W0[(size_t)(1 + ks*32 + k0q + j)*128 + n]; // rows 1..64
                wf0[i][ks] = f;
            }
            #pragma unroll
            for (int ks = 0; ks < 4; ++ks) {
                half8 f;
                #pragma unroll
                for (int j = 0; j < 8; ++j)
                    f[j] = (h16)W1[(size_t)(ks*32 + k0q + j)*128 + n];
                wf1f[i][ks] = f;
            }
        }
        #pragma unroll
        for (int ks = 0; ks < 4; ++ks) {
            half8 f;
            #pragma unroll
            for (int j = 0; j < 8; ++j)
                f[j] = (h16)W2[(size_t)(ks*32 + k0q + j)*64 + nt3*16 + ln];
            wf3[ks] = f;
        }
    }
    float w0r0[2] = { W0[nt0*16+ln], W0[nt1*16+ln] };  // W0 row 0 (x rank-1)
    float b0r[2]  = { b0[nt0*16+ln], b0[nt1*16+ln] };
    float b1r[2]  = { b1[nt0*16+ln], b1[nt1*16+ln] };
    float b2r     =   b2[nt3*16+ln];

    // ---- stage x chunk 0, zero initial state ----
    for (int i = tid; i < NB*NODE*TB; i += 256) {
        int t = i & 31; int rn = i >> 5; int n = rn % NODE; int e = rn / NODE;
        sx[0][e][n][t] = (h16)x[((size_t)(bbase+e)*NODE + n)*TT + t];
    }
    for (int i = tid; i < MR*64; i += 256) {
        int r = i >> 6, k = i & 63;
        sg[r*LDK + k] = (h16)0.f;
    }
    __syncthreads();
    if (tid < MR) {
        int b = tid / NODE, i = tid % NODE;
        float acc = 0.f;
        #pragma unroll
        for (int j = 0; j < NODE; ++j) acc += af[i][j]*(float)sx[0][b][j][0];
        sxg[tid] = acc;
    }
    __syncthreads();

    #pragma unroll 1
    for (int tc = 0; tc < TT/TB; ++tc) {
        if (tc+1 < TT/TB) {   // stage next chunk (read >=31 barriers later)
            for (int i = tid; i < NB*NODE*TB; i += 256) {
                int t = i & 31; int rn = i >> 5; int n = rn % NODE; int e = rn / NODE;
                sx[(tc+1)&1][e][n][t] =
                    (h16)x[((size_t)(bbase+e)*NODE + n)*TT + (tc+1)*TB + t];
            }
        }
        #pragma unroll 1
        for (int tt = 0; tt < TB; ++tt) {
            const int t = tc*TB + tt;
            // ---------------- L1: h1 = relu( gS @ W0' + x*w0r0 + b0 ) ------
            #pragma unroll
            for (int mt = 0; mt < 5; ++mt) {
                half8 a0 = *(const half8*)&sg[(mt*16+ln)*LDK + 0  + k0q];
                half8 a1 = *(const half8*)&sg[(mt*16+ln)*LDK + 32 + k0q];
                float xga[4];
                #pragma unroll
                for (int r = 0; r < 4; ++r) xga[r] = sxg[mt*16 + q*4 + r];
                #pragma unroll
                for (int i = 0; i < 2; ++i) {
                    float4v acc = {0.f,0.f,0.f,0.f};
                    acc = __builtin_amdgcn_mfma_f32_16x16x32_f16(a0, wf0[i][0], acc, 0,0,0);
                    acc = __builtin_amdgcn_mfma_f32_16x16x32_f16(a1, wf0[i][1], acc, 0,0,0);
                    #pragma unroll
                    for (int r = 0; r < 4; ++r) {
                        float v = acc[r] + b0r[i] + xga[r]*w0r0[i];
                        sh[(mt*16+q*4+r)*LDK + (2*w+i)*16 + ln] = (h16)fmaxf(v, 0.f);
                    }
                }
            }
            __syncthreads();
            // ---------------- M1: g1 = A @ h1 (packed f16) ----------------
            {
                int b = tid >> 4, ko = tid & 15;
                const h16* base = &sh[(b*NODE)*LDK + ko*8];
                half2v v[NODE][4];
                #pragma unroll
                for (int j = 0; j < NODE; ++j) {
                    const half2v* p = (const half2v*)(base + j*LDK);
                    v[j][0]=p[0]; v[j][1]=p[1]; v[j][2]=p[2]; v[j][3]=p[3];
                }
                h16* outb = &sg[(b*NODE)*LDK + ko*8];
                #pragma unroll
                for (int i = 0; i < NODE; ++i) {
                    half2v a0={(h16)0,(h16)0}, a1=a0, a2=a0, a3=a0;
                    #pragma unroll
                    for (int j = 0; j < NODE; ++j) {
                        half2v aa = { ah[i][j], ah[i][j] };
                        a0 += aa*v[j][0]; a1 += aa*v[j][1];
                        a2 += aa*v[j][2]; a3 += aa*v[j][3];
                    }
                    half2v* po = (half2v*)(outb + i*LDK);
                    po[0]=a0; po[1]=a1; po[2]=a2; po[3]=a3;
                }
            }
            __syncthreads();
            // ---------------- L2: h2 = relu( g1 @ W1 + b1 ) ---------------
            #pragma unroll
            for (int mt = 0; mt < 5; ++mt) {
                half8 a[4];
                #pragma unroll
                for (int ks = 0; ks < 4; ++ks)
                    a[ks] = *(const half8*)&sg[(mt*16+ln)*LDK + ks*32 + k0q];
                #pragma unroll
                for (int i = 0; i < 2; ++i) {
                    float4v acc = {0.f,0.f,0.f,0.f};
                    #pragma unroll
                    for (int ks = 0; ks < 4; ++ks)
                        acc = __builtin_amdgcn_mfma_f32_16x16x32_f16(a[ks], wf1f[i][ks], acc, 0,0,0);
                    #pragma unroll
                    for (int r = 0; r < 4; ++r) {
                        float v = fmaxf(acc[r] + b1r[i], 0.f);
                        sh[(mt*16+q*4+r)*LDK + (2*w+i)*16 + ln] = (h16)v;
                    }
                }
            }
            __syncthreads();
            // ---------------- M2: g2 = A @ h2 -----------------------------
            {
                int b = tid >> 4, ko = tid & 15;
                const h16* base = &sh[(b*NODE)*LDK + ko*8];
                half2v v[NODE][4];
                #pragma unroll
                for (int j = 0; j < NODE; ++j) {
                    const half2v* p = (const half2v*)(base + j*LDK);
                    v[j][0]=p[0]; v[j][1]=p[1]; v[j][2]=p[2]; v[j][3]=p[3];
                }
                h16* outb = &sg[(b*NODE)*LDK + ko*8];
                #pragma unroll
                for (int i = 0; i < NODE; ++i) {
                    half2v a0={(h16)0,(h16)0}, a1=a0, a2=a0, a3=a0;
                    #pragma unroll
                    for (int j = 0; j < NODE; ++j) {
                        half2v aa = { ah[i][j], ah[i][j] };
                        a0 += aa*v[j][0]; a1 += aa*v[j][1];
                        a2 += aa*v[j][2]; a3 += aa*v[j][3];
                    }
                    half2v* po = (half2v*)(outb + i*LDK);
                    po[0]=a0; po[1]=a1; po[2]=a2; po[3]=a3;
                }
            }
            __syncthreads();
            // ---------------- L3: state = tanh( g2 @ W2 + b2 ) ------------
            #pragma unroll
            for (int mt = 0; mt < 5; ++mt) {
                half8 a[4];
                #pragma unroll
                for (int ks = 0; ks < 4; ++ks)
                    a[ks] = *(const half8*)&sg[(mt*16+ln)*LDK + ks*32 + k0q];
                float4v acc = {0.f,0.f,0.f,0.f};
                #pragma unroll
                for (int ks = 0; ks < 4; ++ks)
                    acc = __builtin_amdgcn_mfma_f32_16x16x32_f16(a[ks], wf3[ks], acc, 0,0,0);
                #pragma unroll
                for (int r = 0; r < 4; ++r) {
                    float z = acc[r] + b2r;
                    float e = __expf(-2.f*fabsf(z));
                    float th = copysignf((1.f - e)/(1.f + e), z);
                    sh[(mt*16+q*4+r)*LDK + nt3*16 + ln] = (h16)th;
                }
            }
            __syncthreads();
            // ------- M3: gS = A @ state (f32 acc) + xg for t+1 ------------
            if (tid < 128) {
                int b = tid >> 3, ko = tid & 7;
                const h16* base = &sh[(b*NODE)*LDK + ko*8];
                float v[NODE][8];
                #pragma unroll
                for (int j = 0; j < NODE; ++j) {
                    half8 hv = *(const half8*)(base + j*LDK);
                    #pragma unroll
                    for (int c = 0; c < 8; ++c) v[j][c] = (float)hv[c];
                }
                h16* outb = &sg[(b*NODE)*LDK + ko*8];
                #pragma unroll
                for (int i = 0; i < NODE; ++i) {
                    half8 o;
                    #pragma unroll
                    for (int c = 0; c < 8; ++c) {
                        float acc = 0.f;
                        #pragma unroll
                        for (int j = 0; j < NODE; ++j) acc += af[i][j]*v[j][c];
                        o[c] = (h16)acc;
                    }
                    *(half8*)(outb + i*LDK) = o;
                }
            } else if (tid < 128 + MR) {
                int t2 = t + 1;
                if (t2 < TT) {
                    int tl = tid - 128;
                    int b = tl / NODE, i = tl % NODE;
                    int buf = (t2 >> 5) & 1, ti = t2 & 31;
                    float acc = 0.f;
                    #pragma unroll
                    for (int j = 0; j < NODE; ++j)
                        acc += af[i][j]*(float)sx[buf][b][j][ti];
                    sxg[tl] = acc;
                }
            }
            __syncthreads();
        }
    }

    // ---- epilogue: xs[b] = [x_end(5) | state(5*64)] (state is raw, in sh) ----
    {
        int e = tid >> 4, f = tid & 15;
        size_t ob = (size_t)(bbase+e)*XS_DIM;
        #pragma unroll
        for (int n = 0; n < NODE; ++n)
            #pragma unroll
            for (int c = 0; c < 4; ++c)
                xs[ob + 5 + n*64 + f*4 + c] = (float)sh[(e*NODE+n)*LDK + f*4 + c];
        if (f < NODE)
            xs[ob + f] = (float)sx[1][e][f][31];   // chunk 15 -> buf 1, t=511
    }
}

// ---------------------------------------------------------------------------
// Kernel B: h = relu(xs @ fc1_w + fc1_b) + per-column sum/sumsq for BN.
// ---------------------------------------------------------------------------
__global__ __launch_bounds__(256) void fc1_kernel(
    const float* __restrict__ xs, const float* __restrict__ fc1_w,
    const float* __restrict__ fc1_b, float* __restrict__ h,
    float* __restrict__ sums)
{
    __shared__ float s_xs[16*XS_DIM];
    const int tid = threadIdx.x;
    const int r0 = blockIdx.x * 16;
    for (int i = tid; i < 16*XS_DIM; i += 256)
        s_xs[i] = xs[(size_t)r0*XS_DIM + i];
    __syncthreads();

    float acc[16];
    #pragma unroll
    for (int r = 0; r < 16; ++r) acc[r] = 0.f;
    for (int k = 0; k < XS_DIM; ++k) {
        float wv = fc1_w[(size_t)k*H2 + tid];
        #pragma unroll
        for (int r = 0; r < 16; ++r) acc[r] += s_xs[r*XS_DIM + k]*wv;
    }
    float bb = fc1_b[tid];
    float ls = 0.f, lq = 0.f;
    #pragma unroll
    for (int r = 0; r < 16; ++r) {
        float v = fmaxf(acc[r] + bb, 0.f);
        h[(size_t)(r0+r)*H2 + tid] = v;
        ls += v; lq += v*v;
    }
    atomicAdd(&sums[tid], ls);
    atomicAdd(&sums[H2 + tid], lq);
}

// ---------------------------------------------------------------------------
// Kernel C: BN(train) normalize + fc2 + softmax. One wave per row.
// ---------------------------------------------------------------------------
__global__ __launch_bounds__(256) void head_kernel(
    const float* __restrict__ h, const float* __restrict__ sums,
    const float* __restrict__ gamma, const float* __restrict__ beta,
    const float* __restrict__ fc2_w, const float* __restrict__ fc2_b,
    float* __restrict__ out)
{
    const int lane = threadIdx.x & 63;
    const int r = blockIdx.x*4 + (threadIdx.x >> 6);
    const int c0 = lane*4;

    float4 hv = *(const float4*)&h[(size_t)r*H2 + c0];
    float hvv[4] = {hv.x, hv.y, hv.z, hv.w};
    float y[4];
    #pragma unroll
    for (int c = 0; c < 4; ++c) {
        int cc = c0 + c;
        float mean = sums[cc] * (1.f/NBATCH);
        float var  = sums[H2+cc]*(1.f/NBATCH) - mean*mean;
        float rstd = rsqrtf(var + EPS);
        y[c] = (hvv[c] - mean)*rstd*gamma[cc] + beta[cc];
    }
    float lg[7];
    #pragma unroll
    for (int j = 0; j < 7; ++j) {
        float p = 0.f;
        #pragma unroll
        for (int c = 0; c < 4; ++c) p += y[c]*fc2_w[(size_t)(c0+c)*7 + j];
        #pragma unroll
        for (int off = 32; off >= 1; off >>= 1) p += __shfl_xor(p, off, 64);
        lg[j] = p + fc2_b[j];
    }
    if (lane == 0) {
        float m = lg[0];
        #pragma unroll
        for (int j = 1; j < 7; ++j) m = fmaxf(m, lg[j]);
        float ev[7]; float s = 0.f;
        #pragma unroll
        for (int j = 0; j < 7; ++j) { ev[j] = expf(lg[j]-m); s += ev[j]; }
        float inv = 1.f/s;
        #pragma unroll
        for (int j = 0; j < 7; ++j) out[(size_t)r*7 + j] = ev[j]*inv;
    }
}

// ---------------------------------------------------------------------------
extern "C" void kernel_launch(void* const* d_in, const int* in_sizes, int n_in,
                              void* d_out, int out_size, void* d_ws, size_t ws_size,
                              hipStream_t stream)
{
    (void)in_sizes; (void)n_in; (void)out_size; (void)ws_size;
    const float* x     = (const float*)d_in[0];
    const float* adj   = (const float*)d_in[1];
    const float* W0    = (const float*)d_in[2];
    const float* b0    = (const float*)d_in[3];
    const float* W1    = (const float*)d_in[4];
    const float* b1    = (const float*)d_in[5];
    const float* W2    = (const float*)d_in[6];
    const float* b2    = (const float*)d_in[7];
    const float* fc1w  = (const float*)d_in[8];
    const float* fc1b  = (const float*)d_in[9];
    const float* gamma = (const float*)d_in[10];
    const float* beta  = (const float*)d_in[11];
    const float* fc2w  = (const float*)d_in[12];
    const float* fc2b  = (const float*)d_in[13];
    float* out = (float*)d_out;

    char* ws = (char*)d_ws;
    float* xs   = (float*)(ws);                                  // 8192*325 f32
    float* hbuf = (float*)(ws + 10649600);                       // 8192*256 f32
    float* sums = (float*)(ws + 10649600 + 8388608);             // 512 f32

    hipMemsetAsync(sums, 0, 512*sizeof(float), stream);
    rnn_kernel<<<NBATCH/NB, 256, 0, stream>>>(x, adj, W0, b0, W1, b1, W2, b2, xs);
    fc1_kernel<<<NBATCH/16, 256, 0, stream>>>(xs, fc1w, fc1b, hbuf, sums);
    head_kernel<<<NBATCH/4, 256, 0, stream>>>(hbuf, sums, gamma, beta, fc2w, fc2b, out);
}